// Round 17
// baseline (4633.400 us; speedup 1.0000x reference)
//
#include <hip/hip_runtime.h>
#include <stdint.h>

// LSTM_49357764165950 — MI355X (gfx950), round 17
// = R16 byte-for-byte EXCEPT __launch_bounds__(512, 4).
// R16's (512,2) = 2 waves/EU guarantees only 1 block/CU (k = 2*4/8): half the grid
// was never resident -> partners q8=4..7 never launched -> spin guards expired -> NaN.
// (512,4) guarantees k = 4*4/8 = 2 blocks/CU (VGPR cap 128; working set ~100) ->
// all 512 blocks co-resident, protocol premise restored.
//   Grid 512 = 64 batch-tiles T x 8 gate-chunks q8 (32 h-cols). Block 512 thr =
//   8 waves (hsub 0..1, kq 0..3). Wave: 4 gates x 16 cols x frags {x_kq,h_kq,h_kq+4}.
//   4-way K-reduce via LDS atomicAdd redbuf (R14-verified), read-then-zero.
//   Exchange: R13-verbatim tagged words in d_out (2 slots), degree 8, XCD check 8-wide,
//   early-issue gather, 2 barriers/step, x2 unroll with compile-time CUR.

typedef float  f32x4  __attribute__((ext_vector_type(4)));
typedef float  f32x2  __attribute__((ext_vector_type(2)));
typedef short  bf16x8 __attribute__((ext_vector_type(8)));
typedef unsigned int u32x4 __attribute__((ext_vector_type(4)));
typedef unsigned int u32x2 __attribute__((ext_vector_type(2)));

#define T_STEPS 255
#define ROWB    80
#define FRAGB   1296
#define XB(b)   ((b)*4*FRAGB)           // x bufs: 0, 5184 (4 frags each)
#define HB      10368                   // h tile (single): 8 frags -> end 20736
#define RB_OFF  20736                   // rb[hsub2][kq4][g4][64] f32 = 8KB -> 28928
#define WM_OFF  28928                   // wm0p/wm1p/bemp[160] f32 = 1920 -> 30848
#define SMEM_SZ 30976

#define AG_ST(p, v) __hip_atomic_store((p), (v), __ATOMIC_RELAXED, __HIP_MEMORY_SCOPE_AGENT)
#define AG_LD(p)    __hip_atomic_load((p),        __ATOMIC_RELAXED, __HIP_MEMORY_SCOPE_AGENT)

__device__ __forceinline__ unsigned short f2bf(float f){
  union { float f; unsigned int u; } v; v.f = f;
  unsigned int u = v.u;
  return (unsigned short)((u + 0x7fffu + ((u >> 16) & 1u)) >> 16);   // RTNE
}
__device__ __forceinline__ float sigf(float x){
  float e = __builtin_amdgcn_exp2f(-1.4426950408889634f * x);
  return __builtin_amdgcn_rcpf(1.0f + e);
}
__device__ __forceinline__ float tanh_(float x){
  float e = __builtin_amdgcn_exp2f(-2.8853900817779268f * x);
  return (1.0f - e) * __builtin_amdgcn_rcpf(1.0f + e);
}

__global__ void zero_ws(unsigned int* flags, unsigned int* outw){
  const unsigned idx = blockIdx.x*512u + threadIdx.x;
  if (idx < 16384u)        AG_ST(flags + idx, 0u);
  else if (idx < 540672u)  AG_ST(outw + (idx - 16384u), 0u);
}

__global__ void __launch_bounds__(512, 4)
lstm_k(const float* __restrict__ obs,
       const float* __restrict__ Wemb, const float* __restrict__ Bemb,
       const float* __restrict__ Wih,  const float* __restrict__ Whh,
       const float* __restrict__ bih,  const float* __restrict__ bhh,
       float* out, unsigned int* flags, unsigned int* hbuf)   // hbuf aliases out
{
  __shared__ __align__(16) char smem[SMEM_SZ];
  const int tid  = threadIdx.x;
  const int l    = tid & 63;
  const int wv   = tid >> 6;           // 0..7
  const int kq   = wv & 3;             // K-quarter
  const int hsub = wv >> 2;            // 16-col group (0..1)
  const int lc   = l & 15;
  const int lg   = l >> 4;
  const int T    = blockIdx.x & 63;    // batch tile (16 rows)
  const int q8   = blockIdx.x >> 6;    // gate-chunk 0..7; partners delta=64 (same XCD)

  // ---- XCD-affinity check, 2 rounds, degree 8 ----
  unsigned xcc;
  asm volatile("s_getreg_b32 %0, hwreg(HW_REG_XCC_ID)" : "=s"(xcc));
  bool fast;
  {
    volatile unsigned* xs = (volatile unsigned*)(smem + WM_OFF);
    if (tid == 0) AG_ST(flags + (T*8 + q8)*16 + 8, 1u + xcc);
    if (tid < 8){
      unsigned v; long g = 0;
      do { v = AG_LD(flags + (T*8 + tid)*16 + 8); } while (v == 0 && ++g < 10000000L);
      xs[tid] = v;
    }
    __syncthreads();
    unsigned ok = 1;
    #pragma unroll
    for (int j = 0; j < 8; ++j) ok &= (xs[j] == 1u + xcc) ? 1u : 0u;
    __syncthreads();
    if (tid == 0) AG_ST(flags + (T*8 + q8)*16 + 9, ok ? 2u : 1u);
    if (tid < 8){
      unsigned v; long g = 0;
      do { v = AG_LD(flags + (T*8 + tid)*16 + 9); } while (v == 0 && ++g < 10000000L);
      xs[tid] = v;
    }
    __syncthreads();
    unsigned all2 = 1;
    #pragma unroll
    for (int j = 0; j < 8; ++j) all2 &= (xs[j] == 2u) ? 1u : 0u;
    fast = (all2 != 0);
    __syncthreads();
  }

  // ---- W fragments: 4 gates x 3 K-frags {x kq, h kq, h kq+4} ----
  const int col = q8*32 + hsub*16 + lc;
  bf16x8 wf[4][3];
  #pragma unroll
  for (int g = 0; g < 4; ++g){
    const int rowg = g*256 + col;
    #pragma unroll
    for (int kfl = 0; kfl < 3; ++kfl){
      const float* src = (kfl == 0) ? (Wih + rowg*128 + kq*32 + lg*8)
                       : (kfl == 1) ? (Whh + rowg*256 + kq*32 + lg*8)
                                    : (Whh + rowg*256 + (kq + 4)*32 + lg*8);
      f32x4 s0 = *(const f32x4*)(src);
      f32x4 s1 = *(const f32x4*)(src + 4);
      bf16x8 v;
      v[0]=(short)f2bf(s0[0]); v[1]=(short)f2bf(s0[1]);
      v[2]=(short)f2bf(s0[2]); v[3]=(short)f2bf(s0[3]);
      v[4]=(short)f2bf(s1[0]); v[5]=(short)f2bf(s1[1]);
      v[6]=(short)f2bf(s1[2]); v[7]=(short)f2bf(s1[3]);
      wf[g][kfl] = v;
    }
  }
  const float bI = bih[       col] + bhh[       col];
  const float bF = bih[256 +  col] + bhh[256 +  col];
  const float bG = bih[512 +  col] + bhh[512 +  col];
  const float bO = bih[768 +  col] + bhh[768 +  col];

  // ---- LDS tables (pad +4 per 16) + tag step (h1/c1 alias rb region) ----
  float* wm0 = (float*)(smem + WM_OFF);        // [160]
  float* wm1 = wm0 + 160;
  float* bem = wm0 + 320;
  if (tid < 128){
    float a = 0.f, b = 0.f, c = 0.f;
    if (tid < 126){ a = 4.0f*Wemb[tid]; b = 4.0f*Wemb[126 + tid]; c = Bemb[tid]; }
    const int pi = tid + (tid >> 4)*4;
    wm0[pi] = a; wm1[pi] = b; bem[pi] = c;
  }
  float* h1f = (float*)(smem + RB_OFF);        // prologue alias
  float* c1f = h1f + 256;
  if (tid < 256){
    const int j = tid;
    float gi  = Wih[(j      )*128 + 126] + bih[j      ] + bhh[j      ];
    float gg2 = Wih[(512 + j)*128 + 126] + bih[512 + j] + bhh[512 + j];
    float go  = Wih[(768 + j)*128 + 126] + bih[768 + j] + bhh[768 + j];
    float c1 = sigf(gi)*tanh_(gg2);
    h1f[j] = sigf(go)*tanh_(c1); c1f[j] = c1;
  }
  __syncthreads();

  // ---- hoisted bases ----
  const int gr = tid >> 5;                     // 0..15 (gather/xtile row)
  const int c8 = (tid & 31) * 8;               // gather cols
  const int cb = (tid & 31) * 4;               // xtile cols
  const int cp = cb + (cb >> 4)*4;             // padded table idx
  const int row_own = lg*4 + kq;               // owned output row
  const float* obs_base = obs + (T*16 + gr)*512;
  char* const gwb  = smem + HB + (c8 >> 5)*FRAGB + gr*ROWB + (c8 & 31)*2;
  char* const xwb  = smem + XB(0) + (cb >> 5)*FRAGB + gr*ROWB + (cb & 31)*2;
  const char* const abx  = smem + XB(0) + kq*FRAGB + lc*ROWB + lg*16;
  const char* const abh0 = smem + HB + kq*FRAGB + lc*ROWB + lg*16;
  const char* const abh4 = smem + HB + (kq + 4)*FRAGB + lc*ROWB + lg*16;
  float* const rbf = (float*)(smem + RB_OFF);
  const int rbase = ((hsub*4 + kq)*4)*64 + l;
  unsigned int* const dstP[2] = { hbuf + 262144 + T*4096 + row_own*256 + col,
                                  hbuf +          T*4096 + row_own*256 + col };
  const unsigned int* const srcP[2] = { hbuf +          T*4096 + gr*256 + c8,
                                        hbuf + 262144 + T*4096 + gr*256 + c8 };

  auto xtile = [&](int buf, float vx, float vy){
    f32x4 wa = *(const f32x4*)(wm0 + cp);
    f32x4 wc = *(const f32x4*)(wm1 + cp);
    f32x4 ba = *(const f32x4*)(bem + cp);
    float e0 = fmaxf(vx*wa[0] + vy*wc[0] + ba[0], 0.f);
    float e1 = fmaxf(vx*wa[1] + vy*wc[1] + ba[1], 0.f);
    float e2 = fmaxf(vx*wa[2] + vy*wc[2] + ba[2], 0.f);
    float e3 = fmaxf(vx*wa[3] + vy*wc[3] + ba[3], 0.f);
    unsigned lo, hi;
    asm("v_cvt_pk_bf16_f32 %0, %1, %2" : "=v"(lo) : "v"(e0), "v"(e1));
    asm("v_cvt_pk_bf16_f32 %0, %1, %2" : "=v"(hi) : "v"(e2), "v"(e3));
    *(u32x2*)(xwb + buf*5184) = (u32x2){lo, hi};
  };

  // c-state + h_tile + x_tile[0]  (read h1f/c1f BEFORE zeroing rb)
  float cs = c1f[col];
  {
    unsigned d0 = (unsigned)f2bf(h1f[c8])     | ((unsigned)f2bf(h1f[c8 + 1]) << 16);
    unsigned d1 = (unsigned)f2bf(h1f[c8 + 2]) | ((unsigned)f2bf(h1f[c8 + 3]) << 16);
    unsigned d2 = (unsigned)f2bf(h1f[c8 + 4]) | ((unsigned)f2bf(h1f[c8 + 5]) << 16);
    unsigned d3 = (unsigned)f2bf(h1f[c8 + 6]) | ((unsigned)f2bf(h1f[c8 + 7]) << 16);
    __syncthreads();                           // all h1/c1 reads done
    *(u32x4*)(gwb) = (u32x4){d0, d1, d2, d3};
    ((f32x4*)rbf)[tid] = (f32x4){0.f, 0.f, 0.f, 0.f};   // zero 8KB rb (512*16B)
  }
  {
    f32x2 p0 = *(const f32x2*)(obs_base), p1 = *(const f32x2*)(obs_base + 2);
    xtile(0, p1[0] - p0[0], p1[1] - p0[1]);
  }
  f32x2 pc0 = *(const f32x2*)(obs_base + 2);
  f32x2 pc1 = *(const f32x2*)(obs_base + 4);
  __syncthreads();

  float hv = 0.f;
  long guard = 0;

#define EXPORTS(KQC)                                                                 \
  { _Pragma("unroll")                                                                \
    for (int j = 0; j < 4; ++j) if (j != (KQC)){                                     \
      const int bj = ((hsub*4 + j)*4)*64 + l;                                        \
      atomicAdd(rbf + bj,       a0[j]);                                              \
      atomicAdd(rbf + bj + 64,  a1[j]);                                              \
      atomicAdd(rbf + bj + 128, a2[j]);                                              \
      atomicAdd(rbf + bj + 192, a3[j]);                                              \
    }                                                                                \
    o0 = a0[(KQC)]; o1 = a1[(KQC)]; o2 = a2[(KQC)]; o3 = a3[(KQC)]; }

#define STEP(CUR, tv, DO_GATHER)                                                     \
  {                                                                                  \
    u32x4 q0, q1;                                                                    \
    if (DO_GATHER && fast){                                                          \
      asm volatile("global_load_dwordx4 %0, %2, off sc0 nt\n\t"                      \
                   "global_load_dwordx4 %1, %2, off offset:16 sc0 nt"                \
                   : "=&v"(q0), "=&v"(q1) : "v"(srcP[CUR]) : "memory");              \
    }                                                                                \
    f32x4 a0 = (f32x4){0.f,0.f,0.f,0.f};                                             \
    f32x4 a1 = (f32x4){0.f,0.f,0.f,0.f};                                             \
    f32x4 a2 = (f32x4){0.f,0.f,0.f,0.f};                                             \
    f32x4 a3 = (f32x4){0.f,0.f,0.f,0.f};                                             \
    {                                                                                \
      bf16x8 ax = *(const bf16x8*)(abx + (CUR)*5184);                                \
      a0 = __builtin_amdgcn_mfma_f32_16x16x32_bf16(ax, wf[0][0], a0, 0, 0, 0);       \
      a1 = __builtin_amdgcn_mfma_f32_16x16x32_bf16(ax, wf[1][0], a1, 0, 0, 0);       \
      a2 = __builtin_amdgcn_mfma_f32_16x16x32_bf16(ax, wf[2][0], a2, 0, 0, 0);       \
      a3 = __builtin_amdgcn_mfma_f32_16x16x32_bf16(ax, wf[3][0], a3, 0, 0, 0);       \
    }                                                                                \
    if ((tv) < T_STEPS - 1){                                                         \
      float vx = pc1[0] - pc0[0], vy = pc1[1] - pc0[1];                              \
      xtile((CUR) ^ 1, vx, vy);                                                      \
    }                                                                                \
    if (DO_GATHER){                                                                  \
      const unsigned want = ((unsigned)(tv)) << 16;                                  \
      unsigned bad;                                                                  \
      if (fast){                                                                     \
        asm volatile("s_waitcnt vmcnt(0)" : "+v"(q0), "+v"(q1) :: "memory");         \
        unsigned x = (q0[0]^want)|(q0[1]^want)|(q0[2]^want)|(q0[3]^want)             \
                   | (q1[0]^want)|(q1[1]^want)|(q1[2]^want)|(q1[3]^want);            \
        bad = x & 0xffff0000u;                                                       \
        while (bad && ++guard < 2000000L){                                           \
          asm volatile("global_load_dwordx4 %0, %2, off sc0 nt\n\t"                  \
                       "global_load_dwordx4 %1, %2, off offset:16 sc0 nt\n\t"        \
                       "s_waitcnt vmcnt(0)"                                          \
                       : "=&v"(q0), "=&v"(q1) : "v"(srcP[CUR]) : "memory");          \
          x = (q0[0]^want)|(q0[1]^want)|(q0[2]^want)|(q0[3]^want)                    \
            | (q1[0]^want)|(q1[1]^want)|(q1[2]^want)|(q1[3]^want);                   \
          bad = x & 0xffff0000u;                                                     \
        }                                                                            \
      } else {                                                                       \
        do {                                                                         \
          _Pragma("unroll")                                                          \
          for (int i = 0; i < 4; ++i){                                               \
            q0[i] = AG_LD(srcP[CUR] + i); q1[i] = AG_LD(srcP[CUR] + 4 + i);          \
          }                                                                          \
          unsigned x = (q0[0]^want)|(q0[1]^want)|(q0[2]^want)|(q0[3]^want)           \
                     | (q1[0]^want)|(q1[1]^want)|(q1[2]^want)|(q1[3]^want);          \
          bad = x & 0xffff0000u;                                                     \
        } while (bad && ++guard < 2000000L);                                         \
      }                                                                              \
      unsigned d0 = (q0[0] & 0xffffu) | (q0[1] << 16);                               \
      unsigned d1 = (q0[2] & 0xffffu) | (q0[3] << 16);                               \
      unsigned d2 = (q1[0] & 0xffffu) | (q1[1] << 16);                               \
      unsigned d3 = (q1[2] & 0xffffu) | (q1[3] << 16);                               \
      *(u32x4*)(gwb) = (u32x4){d0, d1, d2, d3};                                      \
    }                                                                                \
    if ((tv) < T_STEPS - 2){                                                         \
      pc0 = *(const f32x2*)(obs_base + ((tv) + 2)*2);                                \
      pc1 = *(const f32x2*)(obs_base + ((tv) + 2)*2 + 2);                            \
    }                                                                                \
    __syncthreads();  /* barrier A (drains obs prefetch too) */                      \
    {                                                                                \
      bf16x8 ah = *(const bf16x8*)(abh0);                                            \
      a0 = __builtin_amdgcn_mfma_f32_16x16x32_bf16(ah, wf[0][1], a0, 0, 0, 0);       \
      a1 = __builtin_amdgcn_mfma_f32_16x16x32_bf16(ah, wf[1][1], a1, 0, 0, 0);       \
      a2 = __builtin_amdgcn_mfma_f32_16x16x32_bf16(ah, wf[2][1], a2, 0, 0, 0);       \
      a3 = __builtin_amdgcn_mfma_f32_16x16x32_bf16(ah, wf[3][1], a3, 0, 0, 0);       \
      bf16x8 ah2 = *(const bf16x8*)(abh4);                                           \
      a0 = __builtin_amdgcn_mfma_f32_16x16x32_bf16(ah2, wf[0][2], a0, 0, 0, 0);      \
      a1 = __builtin_amdgcn_mfma_f32_16x16x32_bf16(ah2, wf[1][2], a1, 0, 0, 0);      \
      a2 = __builtin_amdgcn_mfma_f32_16x16x32_bf16(ah2, wf[2][2], a2, 0, 0, 0);      \
      a3 = __builtin_amdgcn_mfma_f32_16x16x32_bf16(ah2, wf[3][2], a3, 0, 0, 0);      \
    }                                                                                \
    float o0, o1, o2, o3;                                                            \
    switch (kq){                                                                     \
      case 0: EXPORTS(0); break;                                                     \
      case 1: EXPORTS(1); break;                                                     \
      case 2: EXPORTS(2); break;                                                     \
      default: EXPORTS(3); break;                                                    \
    }                                                                                \
    __syncthreads();  /* barrier B */                                                \
    {                                                                                \
      float gi = o0 + rbf[rbase]       + bI;                                         \
      float gf = o1 + rbf[rbase + 64]  + bF;                                         \
      float gg = o2 + rbf[rbase + 128] + bG;                                         \
      float go = o3 + rbf[rbase + 192] + bO;                                         \
      rbf[rbase] = 0.f; rbf[rbase + 64] = 0.f;                                       \
      rbf[rbase + 128] = 0.f; rbf[rbase + 192] = 0.f;                                \
      cs = sigf(gf)*cs + sigf(gi)*tanh_(gg);                                         \
      hv = sigf(go)*tanh_(cs);                                                       \
    }                                                                                \
    if ((tv) < T_STEPS - 1){                                                         \
      const unsigned want2 = ((unsigned)((tv) + 1)) << 16;                           \
      unsigned pk;                                                                   \
      asm("v_cvt_pk_bf16_f32 %0, %1, %2" : "=v"(pk) : "v"(hv), "v"(hv));             \
      unsigned w0 = want2 | (pk & 0xffffu);                                          \
      if (fast){                                                                     \
        asm volatile("global_store_dword %0, %1, off sc0"                            \
                     :: "v"(dstP[CUR]), "v"(w0) : "memory");                         \
      } else {                                                                       \
        AG_ST(dstP[CUR], w0);                                                        \
      }                                                                              \
    }                                                                                \
  }

  STEP(0, 0, 0)                                  // peel t=0 (no gather)
  for (int t = 1; t < 253; t += 2){
    STEP(1, t, 1)
    STEP(0, t + 1, 1)
  }
  STEP(1, 253, 1)
  STEP(0, 254, 1)
#undef STEP
#undef EXPORTS

  // ---- done-rendezvous (degree 8) before epilogue overwrites hbuf ----
  if (tid == 0) AG_ST(flags + (T*8 + q8)*16 + 10, 1u);
  if (tid < 8){
    unsigned v; long g = 0;
    do { v = AG_LD(flags + (T*8 + tid)*16 + 10); } while (v == 0 && ++g < 10000000L);
  }
  __syncthreads();

  // ---- epilogue: final (h, c) f32, 1 row x 1 col per thread ----
  {
    const int r = T*16 + row_own;
    out[r*256 + col]          = hv;
    out[262144 + r*256 + col] = cs;
  }
}

extern "C" void kernel_launch(void* const* d_in, const int* in_sizes, int n_in,
                              void* d_out, int out_size, void* d_ws, size_t ws_size,
                              hipStream_t stream) {
  (void)in_sizes; (void)n_in; (void)out_size; (void)ws_size;
  const float* obs  = (const float*)d_in[0];
  /* d_in[1] = pooled: unused */
  const float* Wemb = (const float*)d_in[2];
  const float* Bemb = (const float*)d_in[3];
  const float* Wih  = (const float*)d_in[4];
  const float* Whh  = (const float*)d_in[5];
  const float* bih  = (const float*)d_in[6];
  const float* bhh  = (const float*)d_in[7];
  float* out = (float*)d_out;
  unsigned int* flags = (unsigned int*)d_ws;
  unsigned int* hbuf  = (unsigned int*)d_out;

  zero_ws<<<dim3(1056), dim3(512), 0, stream>>>(flags, hbuf);
  lstm_k<<<dim3(512), dim3(512), 0, stream>>>(obs, Wemb, Bemb, Wih, Whh, bih, bhh,
                                              out, flags, hbuf);
}

// Round 18
// 387.525 us; speedup vs baseline: 11.9564x; 11.9564x over previous
//
#include <hip/hip_runtime.h>
#include <stdint.h>

// LSTM_49357764165950 — MI355X (gfx950), round 18 = R13 VERBATIM (re-anchor).
// R13 is the verified best (386us): 256 blocks x 512 thr (8 waves = 2/SIMD),
// register-resident W (wf[4][6], 96 VGPR), K-half redbuf, pipelined tagged-word
// exchange in d_out (2 slots, XCD check deg-4), x2 unroll w/ compile-time CUR,
// carried obs prefetch, early-issue gather, 2 barriers/step.
// R14-R17 established: any launch shape guaranteeing >2 waves/SIMD clamps VGPR
// to <=64 and spills the ~100-VGPR working set (64-VGPR + WRITE>>10MB signature),
// so this 2-waves/SIMD structure is the compiler-feasible optimum for this design.

typedef float  f32x4  __attribute__((ext_vector_type(4)));
typedef float  f32x2  __attribute__((ext_vector_type(2)));
typedef short  bf16x8 __attribute__((ext_vector_type(8)));
typedef unsigned int u32x4 __attribute__((ext_vector_type(4)));
typedef unsigned int u32x2 __attribute__((ext_vector_type(2)));

#define T_STEPS 255
#define ROWB    80
#define FRAGB   1312
#define XTO(b)  ((b)*4*FRAGB)            // 0, 5248
#define HTO(b)  (10496 + (b)*8*FRAGB)    // 10496, 20992 (end 31488)
#define RB_OFF  31488
#define WM_OFF  47872
#define H1_OFF  49792
#define C1_OFF  50816
#define SMEM_SZ 52224

#define AG_ST(p, v) __hip_atomic_store((p), (v), __ATOMIC_RELAXED, __HIP_MEMORY_SCOPE_AGENT)
#define AG_LD(p)    __hip_atomic_load((p),        __ATOMIC_RELAXED, __HIP_MEMORY_SCOPE_AGENT)

__device__ __forceinline__ unsigned short f2bf(float f){
  union { float f; unsigned int u; } v; v.f = f;
  unsigned int u = v.u;
  return (unsigned short)((u + 0x7fffu + ((u >> 16) & 1u)) >> 16);   // RTNE
}
__device__ __forceinline__ float sigf(float x){
  float e = __builtin_amdgcn_exp2f(-1.4426950408889634f * x);
  return __builtin_amdgcn_rcpf(1.0f + e);
}
__device__ __forceinline__ float tanh_(float x){
  float e = __builtin_amdgcn_exp2f(-2.8853900817779268f * x);
  return (1.0f - e) * __builtin_amdgcn_rcpf(1.0f + e);
}

__global__ void zero_ws(unsigned int* flags, unsigned int* outw){
  const unsigned idx = blockIdx.x*512u + threadIdx.x;
  if (idx < 16384u)        AG_ST(flags + idx, 0u);
  else if (idx < 540672u)  AG_ST(outw + (idx - 16384u), 0u);
}

__global__ void __launch_bounds__(512, 2)
lstm_k(const float* __restrict__ obs,
       const float* __restrict__ Wemb, const float* __restrict__ Bemb,
       const float* __restrict__ Wih,  const float* __restrict__ Whh,
       const float* __restrict__ bih,  const float* __restrict__ bhh,
       float* out, unsigned int* flags, unsigned int* hbuf)   // hbuf aliases out
{
  __shared__ __align__(16) char smem[SMEM_SZ];
  const int tid  = threadIdx.x;
  const int l    = tid & 63;
  const int w    = tid >> 6;
  const int hsub = w & 3;
  const int kh   = w >> 2;
  const int lc   = l & 15;
  const int lg   = l >> 4;
  const int T    = blockIdx.x & 63;
  const int q    = blockIdx.x >> 6;

  // ---- XCD-affinity check, 2 rounds, degree 4 ----
  unsigned xcc;
  asm volatile("s_getreg_b32 %0, hwreg(HW_REG_XCC_ID)" : "=s"(xcc));
  bool fast;
  {
    volatile unsigned* xs = (volatile unsigned*)(smem + WM_OFF);
    if (tid == 0) AG_ST(flags + (T*4 + q)*16 + 8, 1u + xcc);
    if (tid < 4){
      unsigned v; long g = 0;
      do { v = AG_LD(flags + (T*4 + tid)*16 + 8); } while (v == 0 && ++g < 10000000L);
      xs[tid] = v;
    }
    __syncthreads();
    unsigned ok = 1;
    #pragma unroll
    for (int j = 0; j < 4; ++j) ok &= (xs[j] == 1u + xcc) ? 1u : 0u;
    __syncthreads();
    if (tid == 0) AG_ST(flags + (T*4 + q)*16 + 9, ok ? 2u : 1u);
    if (tid < 4){
      unsigned v; long g = 0;
      do { v = AG_LD(flags + (T*4 + tid)*16 + 9); } while (v == 0 && ++g < 10000000L);
      xs[tid] = v;
    }
    __syncthreads();
    unsigned all2 = 1;
    #pragma unroll
    for (int j = 0; j < 4; ++j) all2 &= (xs[j] == 2u) ? 1u : 0u;
    fast = (all2 != 0);
    __syncthreads();
  }

  // ---- register-resident W fragments ----
  bf16x8 wf[4][6];
  #pragma unroll
  for (int g = 0; g < 4; ++g){
    const int rowg = g*256 + q*64 + hsub*16 + lc;
    #pragma unroll
    for (int kfl = 0; kfl < 6; ++kfl){
      const float* src;
      if (kfl < 2){
        const int k0 = (kh*2 + kfl)*32 + lg*8;
        src = Wih + rowg*128 + k0;
      } else {
        const int k0 = (kh*4 + kfl - 2)*32 + lg*8;
        src = Whh + rowg*256 + k0;
      }
      f32x4 s0 = *(const f32x4*)(src);
      f32x4 s1 = *(const f32x4*)(src + 4);
      bf16x8 v;
      v[0]=(short)f2bf(s0[0]); v[1]=(short)f2bf(s0[1]);
      v[2]=(short)f2bf(s0[2]); v[3]=(short)f2bf(s0[3]);
      v[4]=(short)f2bf(s1[0]); v[5]=(short)f2bf(s1[1]);
      v[6]=(short)f2bf(s1[2]); v[7]=(short)f2bf(s1[3]);
      wf[g][kfl] = v;
    }
  }
  float bias[4];
  #pragma unroll
  for (int g = 0; g < 4; ++g){
    const int rowg = g*256 + q*64 + hsub*16 + lc;
    bias[g] = (kh == 0) ? (bih[rowg] + bhh[rowg]) : 0.f;
  }

  // ---- LDS tables (padded) + tag step ----
  float* wm0 = (float*)(smem + WM_OFF);
  float* wm1 = wm0 + 160;
  float* bem = wm0 + 320;
  if (tid < 128){
    float a = 0.f, b = 0.f, c = 0.f;
    if (tid < 126){ a = 4.0f*Wemb[tid]; b = 4.0f*Wemb[126 + tid]; c = Bemb[tid]; }
    const int pi = tid + (tid >> 4)*4;
    wm0[pi] = a; wm1[pi] = b; bem[pi] = c;
  }
  float* h1f = (float*)(smem + H1_OFF);
  float* c1f = (float*)(smem + C1_OFF);
  if (tid < 256){
    const int j = tid;
    float gi  = Wih[(j      )*128 + 126] + bih[j      ] + bhh[j      ];
    float gg2 = Wih[(512 + j)*128 + 126] + bih[512 + j] + bhh[512 + j];
    float go  = Wih[(768 + j)*128 + 126] + bih[768 + j] + bhh[768 + j];
    float c1 = sigf(gi)*tanh_(gg2);
    h1f[j] = sigf(go)*tanh_(c1); c1f[j] = c1;
  }
  __syncthreads();

  // ---- hoisted bases ----
  const int gr = tid >> 5;
  const int c8 = (tid & 31) * 8;
  const int col  = q*64 + hsub*16 + lc;
  const int row0 = lg*4 + 2*kh;
  const float* obs_base = obs + (T*16 + gr)*512;
  char* const xwb   = smem + (((tid & 31)*4) >> 5)*FRAGB + gr*ROWB + (((tid & 31)*4) & 31)*2;
  const int  xcp    = ((tid & 31)*4) + (((tid & 31)*4) >> 4)*4;
  char* const gwb   = smem + (c8 >> 5)*FRAGB + gr*ROWB + (c8 & 31)*2;
  const char* const abx = smem + kh*2*FRAGB + lc*ROWB + lg*16;
  const char* const abh = smem + kh*4*FRAGB + lc*ROWB + lg*16;
  f32x2* const rb = (f32x2*)(smem + RB_OFF);
  const int rb_exp = (hsub*2 + (kh ^ 1))*256 + l;
  const int rb_red = (hsub*2 + kh)*256 + l;
  unsigned int* const dstP[2] = { hbuf + 262144 + T*4096 + row0*256 + col,
                                  hbuf +          T*4096 + row0*256 + col };
  const unsigned int* const srcP[2] = { hbuf +          T*4096 + gr*256 + c8,
                                        hbuf + 262144 + T*4096 + gr*256 + c8 };

  auto xtile = [&](int buf, float vx, float vy){
    f32x4 wa = *(const f32x4*)(wm0 + xcp);
    f32x4 wc = *(const f32x4*)(wm1 + xcp);
    f32x4 ba = *(const f32x4*)(bem + xcp);
    float e0 = fmaxf(vx*wa[0] + vy*wc[0] + ba[0], 0.f);
    float e1 = fmaxf(vx*wa[1] + vy*wc[1] + ba[1], 0.f);
    float e2 = fmaxf(vx*wa[2] + vy*wc[2] + ba[2], 0.f);
    float e3 = fmaxf(vx*wa[3] + vy*wc[3] + ba[3], 0.f);
    unsigned lo, hi;
    asm("v_cvt_pk_bf16_f32 %0, %1, %2" : "=v"(lo) : "v"(e0), "v"(e1));
    asm("v_cvt_pk_bf16_f32 %0, %1, %2" : "=v"(hi) : "v"(e2), "v"(e3));
    *(u32x2*)(xwb + XTO(0) + buf*XTO(1)) = (u32x2){lo, hi};
  };

  // c-state + h_tile[0] + x_tile[0]
  float cs0, cs1;
  { float cv = c1f[col]; cs0 = cv; cs1 = cv; }
  {
    bf16x8 v;
    #pragma unroll
    for (int i = 0; i < 8; ++i) v[i] = (short)f2bf(h1f[c8 + i]);
    *(bf16x8*)(gwb + HTO(0)) = v;
  }
  {
    f32x2 p0 = *(const f32x2*)(obs_base), p1 = *(const f32x2*)(obs_base + 2);
    xtile(0, p1[0] - p0[0], p1[1] - p0[1]);
  }
  f32x2 pc0 = *(const f32x2*)(obs_base + 2);
  f32x2 pc1 = *(const f32x2*)(obs_base + 4);
  __syncthreads();

  float hv0 = 0.f, hv1 = 0.f;
  long guard = 0;

#define STEP(CUR, tv, DO_GATHER)                                                     \
  {                                                                                  \
    u32x4 q0, q1;                                                                    \
    if (DO_GATHER && fast){                                                          \
      asm volatile("global_load_dwordx4 %0, %2, off sc0 nt\n\t"                      \
                   "global_load_dwordx4 %1, %2, off offset:16 sc0 nt"                \
                   : "=&v"(q0), "=&v"(q1) : "v"(srcP[CUR]) : "memory");              \
    }                                                                                \
    f32x4 acc0 = (f32x4){bias[0],bias[0],bias[0],bias[0]};                           \
    f32x4 acc1 = (f32x4){bias[1],bias[1],bias[1],bias[1]};                           \
    f32x4 acc2 = (f32x4){bias[2],bias[2],bias[2],bias[2]};                           \
    f32x4 acc3 = (f32x4){bias[3],bias[3],bias[3],bias[3]};                           \
    _Pragma("unroll")                                                                \
    for (int kfl = 0; kfl < 2; ++kfl){                                               \
      bf16x8 a = *(const bf16x8*)(abx + XTO(CUR) + kfl*FRAGB);                       \
      acc0 = __builtin_amdgcn_mfma_f32_16x16x32_bf16(a, wf[0][kfl], acc0, 0, 0, 0);  \
      acc1 = __builtin_amdgcn_mfma_f32_16x16x32_bf16(a, wf[1][kfl], acc1, 0, 0, 0);  \
      acc2 = __builtin_amdgcn_mfma_f32_16x16x32_bf16(a, wf[2][kfl], acc2, 0, 0, 0);  \
      acc3 = __builtin_amdgcn_mfma_f32_16x16x32_bf16(a, wf[3][kfl], acc3, 0, 0, 0);  \
    }                                                                                \
    if ((tv) < T_STEPS - 1){                                                         \
      float vx = pc1[0] - pc0[0], vy = pc1[1] - pc0[1];                              \
      xtile((CUR) ^ 1, vx, vy);                                                      \
    }                                                                                \
    if (DO_GATHER){                                                                  \
      const unsigned want = ((unsigned)(tv)) << 16;                                  \
      unsigned bad;                                                                  \
      if (fast){                                                                     \
        asm volatile("s_waitcnt vmcnt(0)" : "+v"(q0), "+v"(q1) :: "memory");         \
        unsigned x = (q0[0]^want)|(q0[1]^want)|(q0[2]^want)|(q0[3]^want)             \
                   | (q1[0]^want)|(q1[1]^want)|(q1[2]^want)|(q1[3]^want);            \
        bad = x & 0xffff0000u;                                                       \
        while (bad && ++guard < 2000000L){                                           \
          asm volatile("global_load_dwordx4 %0, %2, off sc0 nt\n\t"                  \
                       "global_load_dwordx4 %1, %2, off offset:16 sc0 nt\n\t"        \
                       "s_waitcnt vmcnt(0)"                                          \
                       : "=&v"(q0), "=&v"(q1) : "v"(srcP[CUR]) : "memory");          \
          x = (q0[0]^want)|(q0[1]^want)|(q0[2]^want)|(q0[3]^want)                    \
            | (q1[0]^want)|(q1[1]^want)|(q1[2]^want)|(q1[3]^want);                   \
          bad = x & 0xffff0000u;                                                     \
        }                                                                            \
      } else {                                                                       \
        do {                                                                         \
          _Pragma("unroll")                                                          \
          for (int i = 0; i < 4; ++i){                                               \
            q0[i] = AG_LD(srcP[CUR] + i); q1[i] = AG_LD(srcP[CUR] + 4 + i);          \
          }                                                                          \
          unsigned x = (q0[0]^want)|(q0[1]^want)|(q0[2]^want)|(q0[3]^want)           \
                     | (q1[0]^want)|(q1[1]^want)|(q1[2]^want)|(q1[3]^want);          \
          bad = x & 0xffff0000u;                                                     \
        } while (bad && ++guard < 2000000L);                                         \
      }                                                                              \
      unsigned d0 = (q0[0] & 0xffffu) | (q0[1] << 16);                               \
      unsigned d1 = (q0[2] & 0xffffu) | (q0[3] << 16);                               \
      unsigned d2 = (q1[0] & 0xffffu) | (q1[1] << 16);                               \
      unsigned d3 = (q1[2] & 0xffffu) | (q1[3] << 16);                               \
      *(u32x4*)(gwb + HTO(CUR)) = (u32x4){d0, d1, d2, d3};                           \
    }                                                                                \
    if ((tv) < T_STEPS - 2){                                                         \
      pc0 = *(const f32x2*)(obs_base + ((tv) + 2)*2);                                \
      pc1 = *(const f32x2*)(obs_base + ((tv) + 2)*2 + 2);                            \
    }                                                                                \
    __syncthreads();  /* barrier A: drains obs prefetch too */                       \
    _Pragma("unroll")                                                                \
    for (int kfl = 2; kfl < 6; ++kfl){                                               \
      bf16x8 a = *(const bf16x8*)(abh + HTO(CUR) + (kfl - 2)*FRAGB);                 \
      acc0 = __builtin_amdgcn_mfma_f32_16x16x32_bf16(a, wf[0][kfl], acc0, 0, 0, 0);  \
      acc1 = __builtin_amdgcn_mfma_f32_16x16x32_bf16(a, wf[1][kfl], acc1, 0, 0, 0);  \
      acc2 = __builtin_amdgcn_mfma_f32_16x16x32_bf16(a, wf[2][kfl], acc2, 0, 0, 0);  \
      acc3 = __builtin_amdgcn_mfma_f32_16x16x32_bf16(a, wf[3][kfl], acc3, 0, 0, 0);  \
    }                                                                                \
    {                                                                                \
      f32x2 e0, e1, e2, e3;                                                          \
      if (kh == 0){                                                                  \
        e0 = (f32x2){acc0[2], acc0[3]}; e1 = (f32x2){acc1[2], acc1[3]};              \
        e2 = (f32x2){acc2[2], acc2[3]}; e3 = (f32x2){acc3[2], acc3[3]};              \
      } else {                                                                       \
        e0 = (f32x2){acc0[0], acc0[1]}; e1 = (f32x2){acc1[0], acc1[1]};              \
        e2 = (f32x2){acc2[0], acc2[1]}; e3 = (f32x2){acc3[0], acc3[1]};              \
      }                                                                              \
      rb[rb_exp] = e0; rb[rb_exp + 64] = e1;                                         \
      rb[rb_exp + 128] = e2; rb[rb_exp + 192] = e3;                                  \
    }                                                                                \
    __syncthreads();  /* barrier B */                                                \
    {                                                                                \
      f32x2 r0 = rb[rb_red], r1 = rb[rb_red + 64];                                   \
      f32x2 r2 = rb[rb_red + 128], r3 = rb[rb_red + 192];                            \
      float gi0, gi1, gf0, gf1, gg0, gg1, go0, go1;                                  \
      if (kh == 0){                                                                  \
        gi0 = acc0[0] + r0[0]; gi1 = acc0[1] + r0[1];                                \
        gf0 = acc1[0] + r1[0]; gf1 = acc1[1] + r1[1];                                \
        gg0 = acc2[0] + r2[0]; gg1 = acc2[1] + r2[1];                                \
        go0 = acc3[0] + r3[0]; go1 = acc3[1] + r3[1];                                \
      } else {                                                                       \
        gi0 = acc0[2] + r0[0]; gi1 = acc0[3] + r0[1];                                \
        gf0 = acc1[2] + r1[0]; gf1 = acc1[3] + r1[1];                                \
        gg0 = acc2[2] + r2[0]; gg1 = acc2[3] + r2[1];                                \
        go0 = acc3[2] + r3[0]; go1 = acc3[3] + r3[1];                                \
      }                                                                              \
      cs0 = sigf(gf0)*cs0 + sigf(gi0)*tanh_(gg0);                                    \
      hv0 = sigf(go0)*tanh_(cs0);                                                    \
      cs1 = sigf(gf1)*cs1 + sigf(gi1)*tanh_(gg1);                                    \
      hv1 = sigf(go1)*tanh_(cs1);                                                    \
    }                                                                                \
    if ((tv) < T_STEPS - 1){                                                         \
      const unsigned want2 = ((unsigned)((tv) + 1)) << 16;                           \
      unsigned pk;                                                                   \
      asm("v_cvt_pk_bf16_f32 %0, %1, %2" : "=v"(pk) : "v"(hv0), "v"(hv1));           \
      unsigned w0 = want2 | (pk & 0xffffu);                                          \
      unsigned w1 = want2 | (pk >> 16);                                              \
      if (fast){                                                                     \
        asm volatile("global_store_dword %0, %1, off sc0\n\t"                        \
                     "global_store_dword %0, %2, off offset:1024 sc0"                \
                     :: "v"(dstP[CUR]), "v"(w0), "v"(w1) : "memory");                \
      } else {                                                                       \
        AG_ST(dstP[CUR], w0); AG_ST(dstP[CUR] + 256, w1);                            \
      }                                                                              \
    }                                                                                \
  }

  STEP(0, 0, 0)                                  // peel t=0 (no gather)
  for (int t = 1; t < 253; t += 2){
    STEP(1, t, 1)
    STEP(0, t + 1, 1)
  }
  STEP(1, 253, 1)
  STEP(0, 254, 1)
#undef STEP

  // ---- done-rendezvous (degree 4) before epilogue overwrites hbuf ----
  if (tid == 0) AG_ST(flags + (T*4 + q)*16 + 10, 1u);
  if (tid < 4){
    unsigned v; long g = 0;
    do { v = AG_LD(flags + (T*4 + tid)*16 + 10); } while (v == 0 && ++g < 10000000L);
  }
  __syncthreads();

  // ---- epilogue ----
  {
    const int r = T*16 + row0;
    out[r*256 + col]                = hv0;
    out[(r + 1)*256 + col]          = hv1;
    out[262144 + r*256 + col]       = cs0;
    out[262144 + (r + 1)*256 + col] = cs1;
  }
}

extern "C" void kernel_launch(void* const* d_in, const int* in_sizes, int n_in,
                              void* d_out, int out_size, void* d_ws, size_t ws_size,
                              hipStream_t stream) {
  (void)in_sizes; (void)n_in; (void)out_size; (void)ws_size;
  const float* obs  = (const float*)d_in[0];
  /* d_in[1] = pooled: unused */
  const float* Wemb = (const float*)d_in[2];
  const float* Bemb = (const float*)d_in[3];
  const float* Wih  = (const float*)d_in[4];
  const float* Whh  = (const float*)d_in[5];
  const float* bih  = (const float*)d_in[6];
  const float* bhh  = (const float*)d_in[7];
  float* out = (float*)d_out;
  unsigned int* flags = (unsigned int*)d_ws;
  unsigned int* hbuf  = (unsigned int*)d_out;

  zero_ws<<<dim3(1056), dim3(512), 0, stream>>>(flags, hbuf);
  lstm_k<<<dim3(256), dim3(512), 0, stream>>>(obs, Wemb, Bemb, Wih, Whh, bih, bhh,
                                              out, flags, hbuf);
}